// Round 18
// baseline (272.654 us; speedup 1.0000x reference)
//
#include <hip/hip_runtime.h>

#define N_NODES 50000
#define E_EDGES 800000
#define F_IN    128
#define EDGE_DIM 64
#define HC      256
#define NEG_SLOPE 0.2f
#define SPLIT_NODE 25000

typedef __attribute__((ext_vector_type(8))) short short8;
typedef __attribute__((ext_vector_type(4))) float f32x4;

__device__ __forceinline__ unsigned short f2bf(float f) {
    unsigned u = __builtin_bit_cast(unsigned, f);
    u += 0x7fffu + ((u >> 16) & 1u);
    return (unsigned short)(u >> 16);
}
__device__ __forceinline__ float bf2f(unsigned short b) {
    return __builtin_bit_cast(float, (unsigned)b << 16);
}

// ---------- K_pre: zero counts, W_T bf16 [256][128], WaT bf16 [16][128], WaE bf16 [16][64] ----------
__global__ __launch_bounds__(256) void k_pre(const float* __restrict__ W,
        const float* __restrict__ att_src, const float* __restrict__ att_dst,
        const float* __restrict__ W_edge, const float* __restrict__ att_edge,
        unsigned short* __restrict__ W_T, unsigned short* __restrict__ WaT,
        unsigned short* __restrict__ WaE, int* __restrict__ counts) {
    int idx = blockIdx.x * 256 + threadIdx.x;
    if (idx < N_NODES) counts[idx] = 0;
    if (idx < 32768) {
        int n = idx >> 7, k = idx & 127;
        W_T[n * 128 + k] = f2bf(W[k * 256 + n]);
    }
    if (idx < 2048) {
        int col = idx & 15, k = idx >> 4;
        const float* att = (col < 8) ? att_src : att_dst;
        int h = col & 7;
        float s = 0.f;
        #pragma unroll
        for (int c = 0; c < 32; ++c)
            s = fmaf(W[k * 256 + h * 32 + c], att[h * 32 + c], s);
        WaT[col * 128 + k] = f2bf(s);
    }
    if (idx < 1024) {
        int c = idx >> 6, k = idx & 63;
        float s = 0.f;
        if (c < 8) {
            #pragma unroll
            for (int cc = 0; cc < 32; ++cc)
                s = fmaf(W_edge[k * 256 + c * 32 + cc], att_edge[c * 32 + cc], s);
        }
        WaE[c * 64 + k] = (c < 8) ? f2bf(s) : (unsigned short)0;
    }
}

// ---------- KBig: GEMM(2-half, ch0 also emits a_src/a_dst via 17th tile) ∥ hist+slot ----------
#define NT_TILES 782
#define GEMM_BLOCKS 512      // bid>>8 = col-half, bid&255 = row-tile start (stride 256)
#define HIST_BLOCKS 782
__global__ __launch_bounds__(256) void kBig(const float* __restrict__ x,
        const unsigned short* __restrict__ W_T, const unsigned short* __restrict__ WaT,
        const int4* __restrict__ dst4, int* __restrict__ counts, int4* __restrict__ slot4,
        unsigned short* __restrict__ xs, float* __restrict__ a_src, float* __restrict__ a_dst) {
    __shared__ __align__(16) unsigned short sB[128 * 128];   // 32 KB (GEMM blocks only)
    int t = threadIdx.x;

    if (blockIdx.x >= GEMM_BLOCKS) {           // ---- histogram + slot assignment
        int i = (blockIdx.x - GEMM_BLOCKS) * 256 + t;
        if (i < E_EDGES / 4) {
            int4 d = dst4[i];
            int4 sl;
            sl.x = atomicAdd(&counts[d.x], 1);
            sl.y = atomicAdd(&counts[d.y], 1);
            sl.z = atomicAdd(&counts[d.z], 1);
            sl.w = atomicAdd(&counts[d.w], 1);
            slot4[i] = sl;
        }
        return;
    }

    // ===== xs-GEMM: ch = column half fixed per block =====
    int ch = blockIdx.x >> 8;
    int rt0 = blockIdx.x & 255;
    for (int G = t; G < 2048; G += 256) {
        int nn = G >> 4, gi = G & 15;
        *(int4*)&sB[(nn * 16 + (gi ^ (nn & 7))) * 8] =
            *(const int4*)&W_T[(ch * 128 + nn) * 128 + gi * 8];
    }
    __syncthreads();
    int lane = t & 63, w = t >> 6, mr = lane & 15, g = lane >> 4;
    short8 wa[4];
    if (ch == 0) {
        #pragma unroll
        for (int ks = 0; ks < 4; ++ks)
            wa[ks] = *(const short8*)&WaT[mr * 128 + ks * 32 + g * 8];
    }

    for (int rt = rt0; rt < NT_TILES; rt += 256) {
        int node = rt * 64 + w * 16 + mr;
        short8 a[4];
        if (node < N_NODES) {
            #pragma unroll
            for (int ks = 0; ks < 4; ++ks) {
                const float* xp = &x[(size_t)node * 128 + ks * 32 + g * 8];
                #pragma unroll
                for (int j = 0; j < 8; ++j) a[ks][j] = (short)f2bf(fmaxf(xp[j], 0.f));
            }
        } else {
            #pragma unroll
            for (int ks = 0; ks < 4; ++ks)
                #pragma unroll
                for (int j = 0; j < 8; ++j) a[ks][j] = 0;
        }

        f32x4 acc[8];
        #pragma unroll
        for (int i = 0; i < 8; ++i) acc[i] = (f32x4){0.f, 0.f, 0.f, 0.f};
        f32x4 acc17 = (f32x4){0.f, 0.f, 0.f, 0.f};

        #pragma unroll
        for (int ks = 0; ks < 4; ++ks) {
            int posk = (ks * 4 + g) ^ (mr & 7);
            #pragma unroll
            for (int nt = 0; nt < 8; ++nt) {
                short8 b = *(const short8*)&sB[((nt * 16 + mr) * 16 + posk) * 8];
                acc[nt] = __builtin_amdgcn_mfma_f32_16x16x32_bf16(a[ks], b, acc[nt], 0, 0, 0);
            }
            if (ch == 0)
                acc17 = __builtin_amdgcn_mfma_f32_16x16x32_bf16(a[ks], wa[ks], acc17, 0, 0, 0);
        }

        #pragma unroll
        for (int r = 0; r < 4; ++r) {
            int node2 = rt * 64 + w * 16 + g * 4 + r;
            if (node2 < N_NODES) {
                #pragma unroll
                for (int nt = 0; nt < 8; ++nt)
                    xs[(size_t)node2 * 256 + ch * 128 + nt * 16 + mr] = f2bf(acc[nt][r]);
                if (ch == 0) {
                    if (mr < 8) a_src[node2 * 8 + mr]       = acc17[r];
                    else        a_dst[node2 * 8 + (mr - 8)] = acc17[r];
                }
            }
        }
    }
}

// ---------- KB_scan: ORDERED exclusive scan (node order) — single block ----------
__global__ __launch_bounds__(1024) void kB_scan(const int* __restrict__ counts,
                                                int* __restrict__ starts) {
    __shared__ int sums[1024];
    int t = threadIdx.x;
    const int chunk = (N_NODES + 1023) / 1024;   // 49
    int begin = t * chunk;
    int end = begin + chunk; if (end > N_NODES) end = N_NODES;
    int s = 0;
    for (int i = begin; i < end && i < N_NODES; ++i) s += counts[i];
    sums[t] = s;
    __syncthreads();
    for (int off = 1; off < 1024; off <<= 1) {
        int tmp = (t >= off) ? sums[t - off] : 0;
        __syncthreads();
        sums[t] += tmp;
        __syncthreads();
    }
    int base = sums[t] - s;
    for (int i = begin; i < end && i < N_NODES; ++i) {
        starts[i] = base;
        base += counts[i];
    }
}

// ---------- KB2: rec4[p] = {e, src, dst, 0} at p = starts[dst]+slot ----------
__global__ __launch_bounds__(256) void kB2(const int* __restrict__ dst,
        const int* __restrict__ slot, const int* __restrict__ starts,
        const int* __restrict__ src, int4* __restrict__ rec4) {
    int e = blockIdx.x * 1024 + threadIdx.x;
    #pragma unroll
    for (int i = 0; i < 4; ++i, e += 256) {
        if (e < E_EDGES) {
            int p = starts[dst[e]] + slot[e];
            rec4[p] = make_int4(e, src[e], dst[e], 0);
        }
    }
}

// ---------- edge tile worker: CSR-order MFMA weights, coalesced w_perm store ----------
__device__ __forceinline__ void edge_tile(int tilebase, int plo, int phi,
        const int4* __restrict__ rec4, const float* __restrict__ ea,
        const unsigned short* __restrict__ WaE,
        const float* __restrict__ a_src, const float* __restrict__ a_dst,
        _Float16* __restrict__ w_perm, int t,
        int* s_e, int* s_sn, int* s_dn, _Float16* s_w) {
    int p = tilebase + t;
    int pc = (p < E_EDGES) ? p : (E_EDGES - 1);
    int4 rv = rec4[pc];
    s_e[t] = rv.x; s_sn[t] = rv.y; s_dn[t] = rv.z;
    __syncthreads();
    int lane = t & 63, w = t >> 6;
    int mr = lane & 15, g = lane >> 4;         // mr = head col, g = k-group
    short8 b0 = *(const short8*)&WaE[mr * 64 + g * 8];
    short8 b1 = *(const short8*)&WaE[mr * 64 + 32 + g * 8];
    #pragma unroll
    for (int ti = 0; ti < 4; ++ti) {
        int lb = w * 64 + ti * 16;
        int e = s_e[lb + mr];
        const float* ap = &ea[(size_t)e * 64 + g * 8];
        short8 a0, a1;
        #pragma unroll
        for (int j = 0; j < 8; ++j) a0[j] = (short)f2bf(ap[j]);
        #pragma unroll
        for (int j = 0; j < 8; ++j) a1[j] = (short)f2bf(ap[32 + j]);
        f32x4 acc = (f32x4){0.f, 0.f, 0.f, 0.f};
        acc = __builtin_amdgcn_mfma_f32_16x16x32_bf16(a0, b0, acc, 0, 0, 0);
        acc = __builtin_amdgcn_mfma_f32_16x16x32_bf16(a1, b1, acc, 0, 0, 0);
        if (mr < 8) {                          // C: col=head=mr, row=g*4+r
            #pragma unroll
            for (int r = 0; r < 4; ++r) {
                int le = lb + g * 4 + r;
                int sn = s_sn[le], dn = s_dn[le];
                float v = acc[r] + a_src[sn * 8 + mr] + a_dst[dn * 8 + mr];
                v = (v > 0.f) ? v : NEG_SLOPE * v;
                s_w[le * 8 + mr] = (_Float16)__expf(v);
            }
        }
    }
    __syncthreads();
    if (p >= plo && p < phi)
        *(int4*)&w_perm[(size_t)p * 8] = *(const int4*)&s_w[t * 8];
}

// ---------- KEdgeA: weights for p in [0, starts[SPLIT_NODE]) ----------
#define EDGE_GRID 1600
__global__ __launch_bounds__(256) void kEdgeA(const float* __restrict__ ea,
        const unsigned short* __restrict__ WaE, const int4* __restrict__ rec4,
        const int* __restrict__ starts,
        const float* __restrict__ a_src, const float* __restrict__ a_dst,
        _Float16* __restrict__ w_perm) {
    __shared__ int s_e[256], s_sn[256], s_dn[256];
    __shared__ _Float16 s_w[256 * 8];
    int bound = starts[SPLIT_NODE];
    int ntile = (bound + 255) >> 8;
    bool first = true;
    for (int tp = blockIdx.x; tp < ntile; tp += EDGE_GRID) {
        if (!first) __syncthreads();
        first = false;
        edge_tile(tp * 256, 0, bound, rec4, ea, WaE, a_src, a_dst, w_perm,
                  threadIdx.x, s_e, s_sn, s_dn, s_w);
    }
}

// ---------- k6 body (wave-per-node, 2 xs-rows per gather) ----------
__device__ __forceinline__ void k6_body(int n, int t,
        const int* __restrict__ starts, const int* __restrict__ counts,
        const _Float16* __restrict__ w_perm, const int4* __restrict__ rec4,
        const unsigned short* __restrict__ xs, const float* __restrict__ bias,
        float* __restrict__ out) {
    int lane = t & 63;
    int start = starts[n], cnt = counts[n];
    int j = lane >> 3;
    int l5 = lane & 31;
    int h2 = lane >> 5;
    int hq = l5 >> 2;

    float acc[8];
    #pragma unroll
    for (int k = 0; k < 8; ++k) acc[k] = 0.f;
    float psum = 0.f;

    for (int base = 0; base < cnt; base += 8) {
        int nk = cnt - base; if (nk > 8) nk = 8;
        float wv = (float)w_perm[(size_t)(start + base) * 8 + lane];
        if (j >= nk) wv = 0.f;
        psum += wv;
        int sv = rec4[start + base + (lane & 7)].y;
        #pragma unroll
        for (int jj = 0; jj < 8; jj += 2) {
            int eidx = jj + h2;
            int s = __shfl(sv, eidx);
            s = (eidx < nk) ? s : 0;
            float w = __shfl(wv, eidx * 8 + hq);
            int4 xv = *(const int4*)&xs[(size_t)s * 256 + l5 * 8];
            acc[0] = fmaf(w, bf2f((unsigned short)(xv.x & 0xffff)), acc[0]);
            acc[1] = fmaf(w, bf2f((unsigned short)((unsigned)xv.x >> 16)), acc[1]);
            acc[2] = fmaf(w, bf2f((unsigned short)(xv.y & 0xffff)), acc[2]);
            acc[3] = fmaf(w, bf2f((unsigned short)((unsigned)xv.y >> 16)), acc[3]);
            acc[4] = fmaf(w, bf2f((unsigned short)(xv.z & 0xffff)), acc[4]);
            acc[5] = fmaf(w, bf2f((unsigned short)((unsigned)xv.z >> 16)), acc[5]);
            acc[6] = fmaf(w, bf2f((unsigned short)(xv.w & 0xffff)), acc[6]);
            acc[7] = fmaf(w, bf2f((unsigned short)((unsigned)xv.w >> 16)), acc[7]);
        }
    }
    #pragma unroll
    for (int k = 0; k < 8; ++k) acc[k] += __shfl_xor(acc[k], 32);
    psum += __shfl_xor(psum, 8);
    psum += __shfl_xor(psum, 16);
    psum += __shfl_xor(psum, 32);
    float denom = __shfl(psum, hq);
    float rinv = 1.0f / (denom + 1e-16f);

    if (h2 == 0) {
        const float* bp = &bias[l5 * 8];
        f32x4 o0, o1;
        #pragma unroll
        for (int k = 0; k < 4; ++k) o0[k] = acc[k] * rinv + bp[k];
        #pragma unroll
        for (int k = 0; k < 4; ++k) o1[k] = acc[4 + k] * rinv + bp[4 + k];
        float* op = &out[(size_t)n * 256 + l5 * 8];
        __builtin_nontemporal_store(o0, (f32x4*)op);
        __builtin_nontemporal_store(o1, (f32x4*)(op + 4));
    }
}

// ---------- KFuse: kEdgeB blocks (p >= bound) first ∥ k6 for nodes [0, SPLIT) ----------
#define K6A_BLOCKS 6250
__global__ __launch_bounds__(256) void kFuse(const float* __restrict__ ea,
        const unsigned short* __restrict__ WaE, const int4* __restrict__ rec4,
        const int* __restrict__ starts, const int* __restrict__ counts,
        const float* __restrict__ a_src, const float* __restrict__ a_dst,
        _Float16* __restrict__ w_perm,
        const unsigned short* __restrict__ xs, const float* __restrict__ bias,
        float* __restrict__ out) {
    __shared__ int s_e[256], s_sn[256], s_dn[256];
    __shared__ _Float16 s_w[256 * 8];
    int t = threadIdx.x;
    if (blockIdx.x < EDGE_GRID) {
        int bound = starts[SPLIT_NODE];
        int tp0 = bound >> 8;
        const int ntile = E_EDGES / 256;       // 3125
        bool first = true;
        for (int tp = tp0 + blockIdx.x; tp < ntile; tp += EDGE_GRID) {
            if (!first) __syncthreads();
            first = false;
            edge_tile(tp * 256, bound, E_EDGES, rec4, ea, WaE, a_src, a_dst, w_perm,
                      t, s_e, s_sn, s_dn, s_w);
        }
        return;
    }
    int n = (blockIdx.x - EDGE_GRID) * 4 + (t >> 6);
    if (n >= SPLIT_NODE) return;
    k6_body(n, t, starts, counts, w_perm, rec4, xs, bias, out);
}

// ---------- K6B: nodes [SPLIT, N) ----------
__global__ __launch_bounds__(256) void k6B(
        const int* __restrict__ starts, const int* __restrict__ counts,
        const _Float16* __restrict__ w_perm, const int4* __restrict__ rec4,
        const unsigned short* __restrict__ xs, const float* __restrict__ bias,
        float* __restrict__ out) {
    int n = SPLIT_NODE + blockIdx.x * 4 + (threadIdx.x >> 6);
    if (n >= N_NODES) return;
    k6_body(n, threadIdx.x, starts, counts, w_perm, rec4, xs, bias, out);
}

extern "C" void kernel_launch(void* const* d_in, const int* in_sizes, int n_in,
                              void* d_out, int out_size, void* d_ws, size_t ws_size,
                              hipStream_t stream) {
    const float* x         = (const float*)d_in[0];
    const int*   ei        = (const int*)d_in[1];   // [2,E]: src = ei, dst = ei+E
    const float* edge_attr = (const float*)d_in[2];
    const float* W         = (const float*)d_in[3];
    const float* att_src   = (const float*)d_in[4];
    const float* att_dst   = (const float*)d_in[5];
    const float* W_edge    = (const float*)d_in[6];
    const float* att_edge  = (const float*)d_in[7];
    const float* bias      = (const float*)d_in[8];
    float* out = (float*)d_out;

    const int* e_src = ei;
    const int* e_dst = ei + E_EDGES;

    char* p = (char*)d_ws;
    unsigned short* xs = (unsigned short*)p; p += (size_t)N_NODES * HC * 2;    // 25.6 MB
    float* a_src   = (float*)p; p += (size_t)N_NODES * 8 * 4;                  // 1.6 MB
    float* a_dst   = (float*)p; p += (size_t)N_NODES * 8 * 4;                  // 1.6 MB
    _Float16* w_perm = (_Float16*)p; p += (size_t)E_EDGES * 8 * 2 + 256;       // 12.8 MB
    int4* rec4     = (int4*)p;  p += (size_t)E_EDGES * 16 + 256;               // 12.8 MB
    int* slot      = (int*)p;   p += (size_t)E_EDGES * 4 + 256;                // 3.2 MB
    unsigned short* W_T  = (unsigned short*)p; p += 32768 * 2;                 // 64 KB
    unsigned short* WaT  = (unsigned short*)p; p += 2048 * 2;                  // 4 KB
    unsigned short* WaE  = (unsigned short*)p; p += 1024 * 2;                  // 2 KB
    int* counts    = (int*)p;   p += 200192;
    int* starts    = (int*)p;   p += 200192;

    hipLaunchKernelGGL(k_pre, dim3(196), dim3(256), 0, stream,
                       W, att_src, att_dst, W_edge, att_edge, W_T, WaT, WaE, counts);
    hipLaunchKernelGGL(kBig, dim3(GEMM_BLOCKS + HIST_BLOCKS), dim3(256), 0, stream,
                       x, W_T, WaT, (const int4*)e_dst, counts, (int4*)slot, xs, a_src, a_dst);
    hipLaunchKernelGGL(kB_scan, dim3(1), dim3(1024), 0, stream, counts, starts);
    hipLaunchKernelGGL(kB2, dim3((E_EDGES + 1023) / 1024), dim3(256), 0, stream,
                       e_dst, slot, starts, e_src, rec4);
    hipLaunchKernelGGL(kEdgeA, dim3(EDGE_GRID), dim3(256), 0, stream,
                       edge_attr, WaE, rec4, starts, a_src, a_dst, w_perm);
    hipLaunchKernelGGL(kFuse, dim3(EDGE_GRID + K6A_BLOCKS), dim3(256), 0, stream,
                       edge_attr, WaE, rec4, starts, counts, a_src, a_dst, w_perm,
                       xs, bias, out);
    hipLaunchKernelGGL(k6B, dim3(K6A_BLOCKS), dim3(256), 0, stream,
                       starts, counts, w_perm, rec4, xs, bias, out);
}

// Round 19
// 208.651 us; speedup vs baseline: 1.3067x; 1.3067x over previous
//
#include <hip/hip_runtime.h>

#define N_NODES 50000
#define E_EDGES 800000
#define F_IN    128
#define EDGE_DIM 64
#define HC      256
#define NEG_SLOPE 0.2f

typedef __attribute__((ext_vector_type(8))) short short8;
typedef __attribute__((ext_vector_type(4))) float f32x4;

__device__ __forceinline__ unsigned short f2bf(float f) {
    unsigned u = __builtin_bit_cast(unsigned, f);
    u += 0x7fffu + ((u >> 16) & 1u);
    return (unsigned short)(u >> 16);
}
__device__ __forceinline__ float bf2f(unsigned short b) {
    return __builtin_bit_cast(float, (unsigned)b << 16);
}

// ---------- K_pre: zero counts/gcur, W_T bf16 [256][128], WaT bf16 [16][128], WaE bf16 [16][64] ----------
__global__ __launch_bounds__(256) void k_pre(const float* __restrict__ W,
        const float* __restrict__ att_src, const float* __restrict__ att_dst,
        const float* __restrict__ W_edge, const float* __restrict__ att_edge,
        unsigned short* __restrict__ W_T, unsigned short* __restrict__ WaT,
        unsigned short* __restrict__ WaE, int* __restrict__ counts, int* __restrict__ gcur) {
    int idx = blockIdx.x * 256 + threadIdx.x;
    if (idx < N_NODES) counts[idx] = 0;
    if (idx == 0) *gcur = 0;
    if (idx < 32768) {
        int n = idx >> 7, k = idx & 127;
        W_T[n * 128 + k] = f2bf(W[k * 256 + n]);
    }
    if (idx < 2048) {
        int col = idx & 15, k = idx >> 4;
        const float* att = (col < 8) ? att_src : att_dst;
        int h = col & 7;
        float s = 0.f;
        #pragma unroll
        for (int c = 0; c < 32; ++c)
            s = fmaf(W[k * 256 + h * 32 + c], att[h * 32 + c], s);
        WaT[col * 128 + k] = f2bf(s);
    }
    if (idx < 1024) {    // WaE[c][k]: B-operand for edge-dot MFMA (cols 8..15 zero)
        int c = idx >> 6, k = idx & 63;
        float s = 0.f;
        if (c < 8) {
            #pragma unroll
            for (int cc = 0; cc < 32; ++cc)
                s = fmaf(W_edge[k * 256 + c * 32 + cc], att_edge[c * 32 + cc], s);
        }
        WaE[c * 64 + k] = (c < 8) ? f2bf(s) : (unsigned short)0;
    }
}

// ---------- K1H: fused — hist blocks compute counts AND slot[e]; rest = MFMA node GEMM ----------
#define NT_TILES 782
#define K1_GRID 512
#define HIST_BLOCKS 782
__global__ __launch_bounds__(256, 2) void k1h(const float* __restrict__ x,
        const unsigned short* __restrict__ W_T, const unsigned short* __restrict__ WaT,
        const int4* __restrict__ dst4, int* __restrict__ counts, int4* __restrict__ slot4,
        unsigned short* __restrict__ xs, float* __restrict__ a_src, float* __restrict__ a_dst) {
    __shared__ unsigned short sB[256 * 128];   // 64 KB, XOR-swizzled 16B granules
    __shared__ unsigned short sA[64 * 128];    // 16 KB
    int t = threadIdx.x;

    if (blockIdx.x < HIST_BLOCKS) {            // ---- histogram + slot assignment
        int i = blockIdx.x * 256 + t;
        if (i < E_EDGES / 4) {
            int4 d = dst4[i];
            int4 sl;
            sl.x = atomicAdd(&counts[d.x], 1);
            sl.y = atomicAdd(&counts[d.y], 1);
            sl.z = atomicAdd(&counts[d.z], 1);
            sl.w = atomicAdd(&counts[d.w], 1);
            slot4[i] = sl;
        }
        return;
    }
    int bid = blockIdx.x - HIST_BLOCKS;        // ---- MFMA part: 0..511

    for (int G = t; G < 4096; G += 256) {
        int n = G >> 4, gi = G & 15;
        *(int4*)&sB[(n * 16 + (gi ^ (n & 7))) * 8] = *(const int4*)&W_T[n * 128 + gi * 8];
    }
    int lane = t & 63, w = t >> 6, mr = lane & 15, g = lane >> 4;
    short8 wa[4];
    #pragma unroll
    for (int ks = 0; ks < 4; ++ks)
        wa[ks] = *(const short8*)&WaT[mr * 128 + ks * 32 + g * 8];

    bool first = true;
    for (int rt = bid; rt < NT_TILES; rt += K1_GRID) {
        if (!first) __syncthreads();
        first = false;
        for (int G = t; G < 1024; G += 256) {
            int r = G >> 4, gi = G & 15;
            int node = rt * 64 + r;
            unsigned short pk[8];
            if (node < N_NODES) {
                const float* xp = &x[(long)node * 128 + gi * 8];
                #pragma unroll
                for (int jj = 0; jj < 8; ++jj) pk[jj] = f2bf(fmaxf(xp[jj], 0.f));
            } else {
                #pragma unroll
                for (int jj = 0; jj < 8; ++jj) pk[jj] = 0;
            }
            *(int4*)&sA[(r * 16 + (gi ^ (r & 7))) * 8] = *(int4*)pk;
        }
        __syncthreads();

        f32x4 acc[17];
        #pragma unroll
        for (int i = 0; i < 17; ++i) acc[i] = (f32x4){0.f, 0.f, 0.f, 0.f};

        int r16 = w * 16 + mr;
        #pragma unroll
        for (int ks = 0; ks < 4; ++ks) {
            int pos = (ks * 4 + g) ^ (mr & 7);
            short8 a = *(const short8*)&sA[(r16 * 16 + pos) * 8];
            #pragma unroll
            for (int nt = 0; nt < 16; ++nt) {
                short8 b = *(const short8*)&sB[((nt * 16 + mr) * 16 + pos) * 8];
                acc[nt] = __builtin_amdgcn_mfma_f32_16x16x32_bf16(a, b, acc[nt], 0, 0, 0);
            }
            acc[16] = __builtin_amdgcn_mfma_f32_16x16x32_bf16(a, wa[ks], acc[16], 0, 0, 0);
        }

        #pragma unroll
        for (int r = 0; r < 4; ++r) {
            int node = rt * 64 + w * 16 + g * 4 + r;
            if (node < N_NODES) {
                #pragma unroll
                for (int nt = 0; nt < 16; ++nt)
                    xs[(long)node * 256 + nt * 16 + mr] = f2bf(acc[nt][r]);
                if (mr < 8) a_src[node * 8 + mr]       = acc[16][r];
                else        a_dst[node * 8 + (mr - 8)] = acc[16][r];
            }
        }
    }
}

// ---------- K4: exclusive-scan counts -> starts via wave scan + global atomic base ----------
__global__ __launch_bounds__(256) void k4_alloc(const int* __restrict__ counts,
                                                int* __restrict__ starts,
                                                int* __restrict__ gcur) {
    int n = blockIdx.x * 256 + threadIdx.x;
    int c = (n < N_NODES) ? counts[n] : 0;
    int incl = c;
    #pragma unroll
    for (int off = 1; off < 64; off <<= 1) {
        int u = __shfl_up(incl, off);
        if ((threadIdx.x & 63) >= off) incl += u;
    }
    int total = __shfl(incl, 63);
    int wavebase = 0;
    if ((threadIdx.x & 63) == 63) wavebase = atomicAdd(gcur, total);
    wavebase = __shfl(wavebase, 63);
    if (n < N_NODES) starts[n] = wavebase + incl - c;
}

// ---------- K25: MFMA edge logits + exp + fp16 scatter — no dot-LDS, no atomics ----------
__global__ __launch_bounds__(256) void k25_mfma(const float* __restrict__ ea,
        const unsigned short* __restrict__ WaE,
        const int* __restrict__ src, const int* __restrict__ dst,
        const int* __restrict__ slot, const int* __restrict__ starts,
        const float* __restrict__ a_src, const float* __restrict__ a_dst,
        _Float16* __restrict__ w_perm, int* __restrict__ src_perm) {
    __shared__ int s_sn[256], s_dn[256], s_pos[256];
    int t = threadIdx.x;
    int blockbase = blockIdx.x * 256;
    {
        int e = blockbase + t;
        int dn = dst[e], sn = src[e];
        int pos = starts[dn] + slot[e];
        s_sn[t] = sn; s_dn[t] = dn; s_pos[t] = pos;
        src_perm[pos] = sn;
    }
    __syncthreads();
    int lane = t & 63, w = t >> 6;
    int mr = lane & 15, g = lane >> 4;    // mr = head (cols), g = k-group
    // B fragments: uniform per lane, L1-hot
    short8 b0 = *(const short8*)&WaE[mr * 64 + g * 8];
    short8 b1 = *(const short8*)&WaE[mr * 64 + 32 + g * 8];

    #pragma unroll
    for (int ti = 0; ti < 4; ++ti) {
        int lb = w * 64 + ti * 16;
        int er = blockbase + lb + mr;
        const float* ap = &ea[(size_t)er * 64 + g * 8];
        short8 a0, a1;
        #pragma unroll
        for (int j = 0; j < 8; ++j) a0[j] = (short)f2bf(ap[j]);
        #pragma unroll
        for (int j = 0; j < 8; ++j) a1[j] = (short)f2bf(ap[32 + j]);
        f32x4 acc = (f32x4){0.f, 0.f, 0.f, 0.f};
        acc = __builtin_amdgcn_mfma_f32_16x16x32_bf16(a0, b0, acc, 0, 0, 0);
        acc = __builtin_amdgcn_mfma_f32_16x16x32_bf16(a1, b1, acc, 0, 0, 0);
        if (mr < 8) {   // C: col=head=mr, row=g*4+r
            #pragma unroll
            for (int r = 0; r < 4; ++r) {
                int le = lb + g * 4 + r;
                int sn = s_sn[le], dn = s_dn[le];
                float v = acc[r] + a_src[sn * 8 + mr] + a_dst[dn * 8 + mr];
                v = (v > 0.f) ? v : NEG_SLOPE * v;
                w_perm[(size_t)s_pos[le] * 8 + mr] = (_Float16)__expf(v);
            }
        }
    }
}

// ---------- K6: wave-per-node streaming normalize + aggregation (fp16 weights) ----------
__global__ __launch_bounds__(256) void k6_wave(
    const int* __restrict__ starts, const int* __restrict__ counts,
    const _Float16* __restrict__ w_perm, const int* __restrict__ src_perm,
    const unsigned short* __restrict__ xs, const float* __restrict__ bias,
    float* __restrict__ out) {
    int lane = threadIdx.x & 63;
    int n = blockIdx.x * 4 + (threadIdx.x >> 6);
    if (n >= N_NODES) return;
    int start = starts[n], cnt = counts[n];
    int j = lane >> 3;        // weight-slot this lane loads
    int hq = lane >> 3;       // head of this lane's 4 output cols (c = lane*4+k)

    float acc0 = 0.f, acc1 = 0.f, acc2 = 0.f, acc3 = 0.f;
    float psum = 0.f;
    for (int base = 0; base < cnt; base += 8) {
        int nk = cnt - base; if (nk > 8) nk = 8;
        float wv = (float)w_perm[(size_t)(start + base) * 8 + lane];   // 128B coalesced
        if (j >= nk) wv = 0.f;
        psum += wv;
        int sv = src_perm[start + base + (lane & 7)];
        #pragma unroll
        for (int jj = 0; jj < 8; ++jj) {
            int s = __shfl(sv, jj);
            s = (jj < nk) ? s : 0;
            float w = __shfl(wv, jj * 8 + hq);
            ushort4 xv = *(const ushort4*)&xs[(size_t)s * 256 + lane * 4];
            acc0 = fmaf(w, bf2f(xv.x), acc0);
            acc1 = fmaf(w, bf2f(xv.y), acc1);
            acc2 = fmaf(w, bf2f(xv.z), acc2);
            acc3 = fmaf(w, bf2f(xv.w), acc3);
        }
    }
    psum += __shfl_xor(psum, 8);
    psum += __shfl_xor(psum, 16);
    psum += __shfl_xor(psum, 32);
    float denom = __shfl(psum, hq);
    float rinv = 1.0f / (denom + 1e-16f);
    float4 bv = *(const float4*)&bias[lane * 4];
    f32x4 o;
    o[0] = acc0 * rinv + bv.x;
    o[1] = acc1 * rinv + bv.y;
    o[2] = acc2 * rinv + bv.z;
    o[3] = acc3 * rinv + bv.w;
    __builtin_nontemporal_store(o, (f32x4*)&out[(size_t)n * 256 + lane * 4]);
}

extern "C" void kernel_launch(void* const* d_in, const int* in_sizes, int n_in,
                              void* d_out, int out_size, void* d_ws, size_t ws_size,
                              hipStream_t stream) {
    const float* x         = (const float*)d_in[0];
    const int*   ei        = (const int*)d_in[1];   // [2,E]: src = ei, dst = ei+E
    const float* edge_attr = (const float*)d_in[2];
    const float* W         = (const float*)d_in[3];
    const float* att_src   = (const float*)d_in[4];
    const float* att_dst   = (const float*)d_in[5];
    const float* W_edge    = (const float*)d_in[6];
    const float* att_edge  = (const float*)d_in[7];
    const float* bias      = (const float*)d_in[8];
    float* out = (float*)d_out;

    const int* e_src = ei;
    const int* e_dst = ei + E_EDGES;

    char* p = (char*)d_ws;
    unsigned short* xs = (unsigned short*)p; p += (size_t)N_NODES * HC * 2;    // 25.6 MB
    float* a_src   = (float*)p; p += (size_t)N_NODES * 8 * 4;                  // 1.6 MB
    float* a_dst   = (float*)p; p += (size_t)N_NODES * 8 * 4;                  // 1.6 MB
    _Float16* w_perm = (_Float16*)p; p += (size_t)E_EDGES * 8 * 2 + 256;       // 12.8 MB (+pad)
    int* src_perm  = (int*)p;   p += (size_t)E_EDGES * 4 + 256;                // 3.2 MB (+pad)
    int* slot      = (int*)p;   p += (size_t)E_EDGES * 4 + 256;                // 3.2 MB (+pad)
    unsigned short* W_T  = (unsigned short*)p; p += 32768 * 2;                 // 64 KB
    unsigned short* WaT  = (unsigned short*)p; p += 2048 * 2;                  // 4 KB
    unsigned short* WaE  = (unsigned short*)p; p += 1024 * 2;                  // 2 KB
    int* counts    = (int*)p;   p += 200192;
    int* starts    = (int*)p;   p += 200192;
    int* gcur      = (int*)p;   p += 256;

    hipLaunchKernelGGL(k_pre, dim3(196), dim3(256), 0, stream,
                       W, att_src, att_dst, W_edge, att_edge, W_T, WaT, WaE, counts, gcur);
    hipLaunchKernelGGL(k1h, dim3(HIST_BLOCKS + K1_GRID), dim3(256), 0, stream,
                       x, W_T, WaT, (const int4*)e_dst, counts, (int4*)slot, xs, a_src, a_dst);
    hipLaunchKernelGGL(k4_alloc, dim3(196), dim3(256), 0, stream,
                       counts, starts, gcur);
    hipLaunchKernelGGL(k25_mfma, dim3(E_EDGES / 256), dim3(256), 0, stream,
                       edge_attr, WaE, e_src, e_dst, slot, starts,
                       a_src, a_dst, w_perm, src_perm);
    hipLaunchKernelGGL(k6_wave, dim3(N_NODES / 4), dim3(256), 0, stream,
                       starts, counts, w_perm, src_perm, xs, bias, out);
}